// Round 9
// baseline (106.763 us; speedup 1.0000x reference)
//
#include <hip/hip_runtime.h>
#include <math.h>

// Adder2D: out[n,co,h,w] = -sum_{ci,kh,kw} |x[n,ci,h+kh-1,w+kw-1] - w[co,ci,kh,kw]|
// x: [16,64,32,32] f32, w: [64,64,3,3] f32, out: [16,64,32,32] f32, pad=1 stride=1.
//
// R10-retry: previous submission died at the container level (same infra
// signature as R6's first attempt, which passed on identical resubmit).
// Source re-audited: all global/LDS accesses bounded, barriers uniform.
// Resubmitted unchanged.
//
// R10: un-serialize the w feed. R8/R9 post-mortem: the per-ci volatile asm
// {s_load + s_waitcnt lgkmcnt(0)} drains ALL outstanding DS reads every ci
// (SMEM and DS share lgkmcnt on gfx9) -> compiler cross-iteration pipelining
// defeated; waves convoy through [SMEM wait][DS wait][VALU] serially.
// Counted-lgkmcnt with hidden SMEM is a correctness hazard (shared counter,
// OOO SMEM completion), so: move w to the vmcnt domain instead. Per ci each
// lane does 9 global_load_dwordx4 from the repacked 256B-aligned slice
// (wave-uniform addr -> coalesced broadcast, L1/L2-hit; w tot 144KB).
// vmcnt is independent of lgkmcnt and these are plain loads -> compiler
// hoists/pipelines across ci freely. 9 VMEM per 288 core VALU (the PX=4
// amortization is what makes VMEM viable; R7's failure was 36 scalar
// VMEM per 144 VALU). Everything else byte-identical to R9.

#define N_   16
#define CI_  64
#define CO_  64
#define HW_  32
#define CG   4      // co per thread (= all of COB)
#define COB  4      // co per block
#define PX   4      // pixels per thread
#define RG   8      // pixel rows per block
#define CIC  16     // ci planes staged per round
#define CPG  4      // ci planes computed per group per round
#define ROWS (RG + 2)
#define LW   34     // col0 = left halo, 1..32 = data, 33 = right halo
#define WSLICE 64   // floats per (cob,ci) w-slice slot (36 used, 256B aligned)

#define XS_WORDS (CIC * ROWS * LW)        // 5440 words = 21760 B

// ---- repack: w[co][ci][t] -> wr[(co/4)*64+ci][ (co&3)*9 + t ], 64-f slots ----
__global__ void repack_w(const float* __restrict__ w, float* __restrict__ wr)
{
    int i  = blockIdx.x * 256 + threadIdx.x;   // 4096 = (co,ci) pairs
    int co = i >> 6;
    int ci = i & 63;
    float* dst = wr + (size_t)((co >> 2) * 64 + ci) * WSLICE + (co & 3) * 9;
    const float* src = w + (size_t)co * (CI_ * 9) + ci * 9;
#pragma unroll
    for (int t = 0; t < 9; ++t) dst[t] = src[t];
}

__global__ __launch_bounds__(256, 3) void adder2d_kernel(
    const float* __restrict__ x, const float* __restrict__ wr,
    float* __restrict__ out)
{
    __shared__ __align__(16) float smem[XS_WORDS];
    float (*xs)[ROWS][LW] = (float (*)[ROWS][LW])smem;   // phase A
    float (*red)[64][16]  = (float (*)[64][16])smem;     // phase B: aliases xs
                                                         // 3*64*16 = 3072 <= 5440 ok

    const int tid = threadIdx.x;
    const int u   = tid & 7;             // col-quad: pixels at cols 4u..4u+3
    const int rl  = (tid >> 3) & 7;      // pixel row within block
    const int cig = tid >> 6;            // ci group: 0..3 (uniform per wave)
    const int r0  = blockIdx.x * RG;
    const int co0 = blockIdx.y * COB;
    const int n   = blockIdx.z;

    const float* wrb = wr + (size_t)blockIdx.y * 64 * WSLICE;

    // ---- zero xs once: halo cols (0,33) and OOB row slots stay zero ----
    for (int i = tid; i < XS_WORDS / 4; i += 256)
        ((float4*)smem)[i] = float4{0.f, 0.f, 0.f, 0.f};

    float acc[PX][CG];
#pragma unroll
    for (int i = 0; i < PX; ++i)
#pragma unroll
        for (int j = 0; j < CG; ++j) acc[i][j] = 0.f;

    const float* xn = x + (size_t)n * CI_ * HW_ * HW_;
    const int pbase = cig * CPG;

    for (int round = 0; round < CI_ / CIC; ++round) {
        const int cc0 = round * CIC;
        __syncthreads();   // protect LDS from previous round's readers
        // ---- stage CIC planes, rows r0-1..r0+8: 1280 float4 units, 5/thread ----
        for (int i = tid; i < CIC * ROWS * (HW_ / 4); i += 256) {
            int plane = i / (ROWS * (HW_ / 4));
            int rem   = i - plane * (ROWS * (HW_ / 4));
            int rr    = rem >> 3;
            int f4    = rem & 7;
            int gr    = r0 - 1 + rr;
            if ((unsigned)gr < HW_) {
                float4 v = ((const float4*)(xn + (size_t)(cc0 + plane) * HW_ * HW_
                                            + gr * HW_))[f4];
                float* dst = &xs[plane][rr][1 + 4 * f4];   // data cols start at 1
                dst[0] = v.x; dst[1] = v.y; dst[2] = v.z; dst[3] = v.w;
            }
        }
        __syncthreads();

#pragma unroll
        for (int cil = 0; cil < CPG; ++cil) {
            const int pl  = pbase + cil;             // per-thread (LDS path)
            const int cis = cc0 + pbase + cil;       // w-slice index

            // ---- w slice (36 floats) as 9 coalesced-broadcast dwordx4,
            //      vmcnt domain: compiler pipelines across ci freely ----
            const float4* p4 = (const float4*)(wrb + (size_t)cis * WSLICE);
            float4 wq[9];
#pragma unroll
            for (int t9 = 0; t9 < 9; ++t9) wq[t9] = p4[t9];

            // x patch for 4 pixels: rows rl..rl+2, storage cols 4u..4u+5
            // (= real cols 4u-1..4u+4, halos pre-zeroed). 3 aligned b64/row.
            float xr[3][6];
#pragma unroll
            for (int kh = 0; kh < 3; ++kh) {
                const float* row = &xs[pl][rl + kh][4 * u];
                float2 a = *(const float2*)&row[0];
                float2 b = *(const float2*)&row[2];
                float2 c = *(const float2*)&row[4];
                xr[kh][0] = a.x; xr[kh][1] = a.y;
                xr[kh][2] = b.x; xr[kh][3] = b.y;
                xr[kh][4] = c.x; xr[kh][5] = c.y;
            }

            // 288 VALU: 4 px x 4 co x 9 taps, v_sub + v_add(abs)
#pragma unroll
            for (int kh = 0; kh < 3; ++kh)
#pragma unroll
                for (int kw = 0; kw < 3; ++kw) {
                    const int t = kh * 3 + kw;
#pragma unroll
                    for (int j = 0; j < CG; ++j) {
                        const int t36 = j * 9 + t;         // compile-time
                        const float4 q = wq[t36 >> 2];
                        const float wjt = (t36 & 3) == 0 ? q.x
                                        : (t36 & 3) == 1 ? q.y
                                        : (t36 & 3) == 2 ? q.z : q.w;
#pragma unroll
                        for (int i = 0; i < PX; ++i)
                            acc[i][j] += fabsf(xr[kh][i + kw] - wjt);
                    }
                }
        }
    }

    // ---- combine the four ci-group partials (red aliases dead xs) ----
    __syncthreads();   // all xs readers done before overwrite
    if (cig != 0) {
        int t = tid & 63;
#pragma unroll
        for (int i = 0; i < PX; ++i)
            *(float4*)&red[cig - 1][t][4 * i] =
                float4{acc[i][0], acc[i][1], acc[i][2], acc[i][3]};
    }
    __syncthreads();
    if (cig == 0) {
#pragma unroll
        for (int g = 0; g < 3; ++g)
#pragma unroll
            for (int i = 0; i < PX; ++i) {
                float4 r = *(const float4*)&red[g][tid][4 * i];
                acc[i][0] += r.x; acc[i][1] += r.y;
                acc[i][2] += r.z; acc[i][3] += r.w;
            }
        float* op = out + (((size_t)n * CO_ + co0) * HW_ + (r0 + rl)) * HW_ + 4 * u;
#pragma unroll
        for (int j = 0; j < CG; ++j)
            *(float4*)&op[(size_t)j * HW_ * HW_] =
                float4{-acc[0][j], -acc[1][j], -acc[2][j], -acc[3][j]};
    }
}

extern "C" void kernel_launch(void* const* d_in, const int* in_sizes, int n_in,
                              void* d_out, int out_size, void* d_ws, size_t ws_size,
                              hipStream_t stream) {
    const float* x  = (const float*)d_in[0];
    const float* wp = (const float*)d_in[1];
    float* out      = (float*)d_out;
    float* wr       = (float*)d_ws;   // 16*64*64*4 = 256 KiB used

    repack_w<<<dim3(16), 256, 0, stream>>>(wp, wr);
    dim3 grid(HW_ / RG, CO_ / COB, N_);   // (4, 16, 16) = 1024 blocks
    adder2d_kernel<<<grid, 256, 0, stream>>>(x, wr, out);
}

// Round 10
// 98.531 us; speedup vs baseline: 1.0835x; 1.0835x over previous
//
#include <hip/hip_runtime.h>
#include <math.h>

// Adder2D: out[n,co,h,w] = -sum_{ci,kh,kw} |x[n,ci,h+kh-1,w+kw-1] - w[co,ci,kh,kw]|
// x: [16,64,32,32] f32, w: [64,64,3,3] f32, out: [16,64,32,32] f32, pad=1 stride=1.
//
// R11: let the COMPILER pipeline the scalar w-feed. R8's volatile asm fused
// {s_load + lgkmcnt(0)} per ci: K$ latency exposed each iteration and all
// outstanding ds_reads drained -> convoy (47.4us, ~50% stall). R10 (VMEM w)
// was worse (57.6us). R7 failed to scalarize only because cig was
// thread-derived; never tried readfirstlane. Now: plain C++ loads through a
// readfirstlane(cig)-uniform pointer -> backend emits s_load itself, hoists
// across the fully-unrolled cil loop (no aliasing stores inside), and owns
// the counted lgkmcnt (its DS waits only get MORE conservative with an
// extra SMEM op in flight -> safe).
// Also: LW 34->35 (odd stride): staging-write banks 1+4f4+3rr mod 32 ->
// <=2-way (free, m136) vs 4-way at LW=34; x reads become 4x b32 per row
// (odd stride kills b64 alignment) = same LDS-pipe cycles, conflict-free.

#define N_   16
#define CI_  64
#define CO_  64
#define HW_  32
#define CG   4      // co per thread (= all of COB)
#define COB  4      // co per block
#define RG   8      // pixel rows per block
#define CIC  16     // ci planes staged per round
#define CPG  4      // ci planes computed per group per round
#define ROWS (RG + 2)
#define LW   35     // word0 = left halo (col -1), 1..32 = cols 0..31, 33 = right halo, 34 pad
#define WSLICE 64   // floats per (cob,ci) w-slice slot (36 used, 256B aligned)

#define XS_WORDS (CIC * ROWS * LW)        // 5600 words = 22400 B

// ---- repack: w[co][ci][t] -> wr[(co/4)*64+ci][ (co&3)*9 + t ], 64-f slots ----
__global__ void repack_w(const float* __restrict__ w, float* __restrict__ wr)
{
    int i  = blockIdx.x * 256 + threadIdx.x;   // 4096 = (co,ci) pairs
    int co = i >> 6;
    int ci = i & 63;
    float* dst = wr + (size_t)((co >> 2) * 64 + ci) * WSLICE + (co & 3) * 9;
    const float* src = w + (size_t)co * (CI_ * 9) + ci * 9;
#pragma unroll
    for (int t = 0; t < 9; ++t) dst[t] = src[t];
}

__global__ __launch_bounds__(512, 4) void adder2d_kernel(
    const float* __restrict__ x, const float* __restrict__ wr,
    float* __restrict__ out)
{
    __shared__ __align__(16) float smem[XS_WORDS];
    float (*xs)[ROWS][LW] = (float (*)[ROWS][LW])smem;   // phase A
    float (*red)[128][8]  = (float (*)[128][8])smem;     // phase B: aliases xs
                                                         // 3*128*8 = 3072 <= 5600 ok

    const int tid = threadIdx.x;
    const int u   = tid & 15;            // col-pair: pixels at cols 2u, 2u+1
    const int rl  = (tid >> 4) & 7;      // pixel row within block
    const int cig = tid >> 7;            // ci group: 0..3 (uniform per wave)
    const int r0  = blockIdx.x * RG;
    const int co0 = blockIdx.y * COB;
    const int n   = blockIdx.z;

    // wave-uniform ci-group index -> SGPR-class; makes the w pointer
    // provably uniform so the compiler scalarizes the loads (s_load).
    const int cigs = __builtin_amdgcn_readfirstlane(cig);
    const float* wrb = wr + (size_t)blockIdx.y * 64 * WSLICE;

    // ---- zero xs once: halo words (0, 33) and OOB row slots stay zero ----
    for (int i = tid; i < XS_WORDS / 4; i += 512)
        ((float4*)smem)[i] = float4{0.f, 0.f, 0.f, 0.f};

    float acc0[CG], acc1[CG];
#pragma unroll
    for (int j = 0; j < CG; ++j) { acc0[j] = 0.f; acc1[j] = 0.f; }

    const float* xn = x + (size_t)n * CI_ * HW_ * HW_;
    const int pbase = cig * CPG;

    for (int round = 0; round < CI_ / CIC; ++round) {
        const int cc0 = round * CIC;
        __syncthreads();   // protect LDS from previous round's readers
        // ---- stage CIC planes, rows r0-1..r0+8: 1280 float4 units ----
        for (int i = tid; i < CIC * ROWS * (HW_ / 4); i += 512) {
            int plane = i / (ROWS * (HW_ / 4));
            int rem   = i - plane * (ROWS * (HW_ / 4));
            int rr    = rem >> 3;
            int f4    = rem & 7;
            int gr    = r0 - 1 + rr;
            if ((unsigned)gr < HW_) {
                float4 v = ((const float4*)(xn + (size_t)(cc0 + plane) * HW_ * HW_
                                            + gr * HW_))[f4];
                float* dst = &xs[plane][rr][1 + 4 * f4];   // data words 1..32
                dst[0] = v.x; dst[1] = v.y; dst[2] = v.z; dst[3] = v.w;
            }
        }
        __syncthreads();

#pragma unroll
        for (int cil = 0; cil < CPG; ++cil) {
            const int pl  = pbase + cil;             // per-thread (LDS path)
            const int cis = cc0 + cigs * CPG + cil;  // uniform (SMEM path)

            // ---- w slice: plain loads from a uniform pointer; compiler
            //      emits s_load and pipelines across the unrolled loop ----
            const float* wu_p = wrb + (size_t)cis * WSLICE;
            float wu[36];
#pragma unroll
            for (int t = 0; t < 36; ++t) wu[t] = wu_p[t];

            // x patch for 2 pixels: rows rl..rl+2, words 2u..2u+3
            // (= real cols 2u-1..2u+2, halos pre-zeroed). Scalar b32 reads:
            // odd LW spreads rows across banks -> conflict-free.
            float xp_[3][4];
#pragma unroll
            for (int kh = 0; kh < 3; ++kh) {
                const float* row = &xs[pl][rl + kh][2 * u];
                xp_[kh][0] = row[0]; xp_[kh][1] = row[1];
                xp_[kh][2] = row[2]; xp_[kh][3] = row[3];
            }

            // 144 VALU: 2 pix x 4 co x 9 taps, v_sub(v,s,v) + v_add(abs)
#pragma unroll
            for (int kh = 0; kh < 3; ++kh)
#pragma unroll
                for (int kw = 0; kw < 3; ++kw) {
                    const int t = kh * 3 + kw;
                    float xa = xp_[kh][kw];
                    float xb = xp_[kh][kw + 1];
#pragma unroll
                    for (int j = 0; j < CG; ++j) {
                        float wjt = wu[j * 9 + t];   // compile-time index
                        acc0[j] += fabsf(xa - wjt);
                        acc1[j] += fabsf(xb - wjt);
                    }
                }
        }
    }

    // ---- combine the four ci-group partials (red aliases dead xs) ----
    __syncthreads();   // all xs readers done before overwrite
    if (cig != 0) {
        int t = tid & 127;
        *(float4*)&red[cig - 1][t][0] = float4{acc0[0], acc0[1], acc0[2], acc0[3]};
        *(float4*)&red[cig - 1][t][4] = float4{acc1[0], acc1[1], acc1[2], acc1[3]};
    }
    __syncthreads();
    if (cig == 0) {
#pragma unroll
        for (int g = 0; g < 3; ++g) {
            float4 ra = *(const float4*)&red[g][tid][0];
            float4 rb = *(const float4*)&red[g][tid][4];
            acc0[0] += ra.x; acc0[1] += ra.y; acc0[2] += ra.z; acc0[3] += ra.w;
            acc1[0] += rb.x; acc1[1] += rb.y; acc1[2] += rb.z; acc1[3] += rb.w;
        }
        float* op = out + (((size_t)n * CO_ + co0) * HW_ + (r0 + rl)) * HW_ + 2 * u;
#pragma unroll
        for (int j = 0; j < CG; ++j)
            *(float2*)&op[(size_t)j * HW_ * HW_] = float2{-acc0[j], -acc1[j]};
    }
}

extern "C" void kernel_launch(void* const* d_in, const int* in_sizes, int n_in,
                              void* d_out, int out_size, void* d_ws, size_t ws_size,
                              hipStream_t stream) {
    const float* x  = (const float*)d_in[0];
    const float* wp = (const float*)d_in[1];
    float* out      = (float*)d_out;
    float* wr       = (float*)d_ws;   // 16*64*64*4 = 256 KiB used

    repack_w<<<dim3(16), 256, 0, stream>>>(wp, wr);
    dim3 grid(HW_ / RG, CO_ / COB, N_);   // (4, 16, 16) = 1024 blocks
    adder2d_kernel<<<grid, 512, 0, stream>>>(x, wr, out);
}